// Round 2
// baseline (160.651 us; speedup 1.0000x reference)
//
#include <hip/hip_runtime.h>
#include <stdint.h>

// ---------------------------------------------------------------------------
// Problem: B=2048, F0=40, D=32, LAYER0=128, LAYER1=128
//   h0[b,s,d]   = relu(sum_{i,j} x[b,i,d] x[b,j,d] W0[i,j,s] + b0[s])
//   nh = h0[:, :64, :], direct0 = h0[:, 64:, :]
//   d1[b,s,d]   = relu(sum_{i,j} x[b,i,d] nh[b,j,d] W1[i,j,s] + b1[s])
//   out[b, 0:64]   = sum_d direct0
//   out[b, 64:192] = sum_d d1
//
// Row-GEMMs over rows r = b*32+d (65536 rows):
//   phase0: K = 40*40 = 1600 (50 k-tiles of 32), P[r,k] = X[r,i]*X[r,j]
//   phase1: K = 40*64 = 2560 (80 k-tiles of 32), P[r,k] = X[r,i]*NH[r,j]
// k-tile t = ic*NJC + jc; k-local kl = ii*8 + jj; i = ic*4+ii, j = jc*8+jj.
// W pre-permuted to bf16 [t][s][32] so both A and B frags are contiguous 16B.
// Block: 128 rows (4 batches) x 128 s, 4 waves (each 64x64), mfma 16x16x32.
// ALL f32->bf16 conversions are RNE (round-to-nearest-even): truncation's
// toward-zero bias accumulated coherently over K=1600/2560 terms and cost us
// absmax 2.50 vs threshold 2.49 in round 1.
// ---------------------------------------------------------------------------

typedef __attribute__((ext_vector_type(8))) short short8;
typedef __attribute__((ext_vector_type(4))) float f32x4;

__device__ __forceinline__ float bf2f(unsigned short v) {
    return __uint_as_float(((unsigned int)v) << 16);
}
__device__ __forceinline__ unsigned short f2bf(float f) {   // RNE
    unsigned int u = __float_as_uint(f);
    u += 0x7FFFu + ((u >> 16) & 1u);
    return (unsigned short)(u >> 16);
}
// pack bf16(lo) | bf16(hi)<<16, RNE both halves
__device__ __forceinline__ unsigned int pack2(float lo, float hi) {
    unsigned int a = __float_as_uint(lo);
    a += 0x7FFFu + ((a >> 16) & 1u);
    unsigned int b = __float_as_uint(hi);
    b += 0x7FFFu + ((b >> 16) & 1u);
    return __builtin_amdgcn_perm(b, a, 0x07060302u);  // hi16(b) | hi16(a)
}
__device__ __forceinline__ float qsum(float v) {  // reduce across the 4 row-quads
    v += __shfl_xor(v, 16, 64);
    v += __shfl_xor(v, 32, 64);
    return v;
}

// W permute+convert: Wp[t][s][kl] = bf16( W[i(t,kl), j(t,kl), s] )
template<int NJC, int JW>
__global__ void permute_w(const float* __restrict__ W, unsigned short* __restrict__ Wp, int total)
{
    int gid = blockIdx.x * 256 + threadIdx.x;
    if (gid >= total) return;
    int kl = gid & 31;
    int s  = (gid >> 5) & 127;
    int t  = gid >> 12;
    int ic = t / NJC;
    int jc = t - ic * NJC;
    int i  = ic * 4 + (kl >> 3);
    int j  = jc * 8 + (kl & 7);
    Wp[gid] = f2bf(W[((size_t)(i * JW + j)) * 128 + s]);
}

// One GEMM phase: T k-tiles, double-buffered P/W in LDS, 1 barrier per k-step.
__device__ __forceinline__ void gemm_phase(
    int T, int NJC,
    const unsigned short* __restrict__ Wp,   // global  [T][128][32] bf16
    const unsigned short* Jbase,             // LDS, this thread's j-source row
    const unsigned short* Xrow,              // LDS, this thread's i-source row (X, stride 40)
    unsigned short* Pl, unsigned short* Wl,  // LDS double buffers [2][128][40]
    f32x4 acc[4][4], int tid)
{
    const int lane = tid & 63;
    const int rl   = tid >> 1;        // build row 0..127
    const int h    = tid & 1;         // build half (16 k's)
    const int mw   = (tid >> 6) & 1;  // wave row-half
    const int nw   = tid >> 7;        // wave col-half
    const int ml   = lane & 15;
    const int kq   = (lane >> 4) << 3;           // k-chunk elem offset
    const int abase = (mw * 64 + ml) * 40 + kq;  // A frag addr (P rows)
    const int bbase = (nw * 64 + ml) * 40 + kq;  // B frag addr (W rows = s)
    const int woff  = rl * 32 + h * 16;          // this thread's slice of a W tile

    auto stage_w = [&](int nbuf, uint4 wa, uint4 wb) {
        unsigned short* wd = Wl + nbuf * 5120 + rl * 40 + h * 16;
        *(uint4*)wd       = wa;
        *(uint4*)(wd + 8) = wb;
    };
    auto build_tile = [&](int nbuf, int ic, int jc) {
        uint4 jv = *(const uint4*)(Jbase + jc * 8);
        float xj0 = __uint_as_float(jv.x << 16);
        float xj1 = __uint_as_float(jv.x & 0xFFFF0000u);
        float xj2 = __uint_as_float(jv.y << 16);
        float xj3 = __uint_as_float(jv.y & 0xFFFF0000u);
        float xj4 = __uint_as_float(jv.z << 16);
        float xj5 = __uint_as_float(jv.z & 0xFFFF0000u);
        float xj6 = __uint_as_float(jv.w << 16);
        float xj7 = __uint_as_float(jv.w & 0xFFFF0000u);
        int   i0  = ic * 4 + 2 * h;
        float xi0 = bf2f(Xrow[i0]);
        float xi1 = bf2f(Xrow[i0 + 1]);
        // bf16*bf16 products are EXACT in f32; pack2 adds exactly one RNE.
        uint4 o0 = make_uint4(pack2(xi0 * xj0, xi0 * xj1), pack2(xi0 * xj2, xi0 * xj3),
                              pack2(xi0 * xj4, xi0 * xj5), pack2(xi0 * xj6, xi0 * xj7));
        uint4 o1 = make_uint4(pack2(xi1 * xj0, xi1 * xj1), pack2(xi1 * xj2, xi1 * xj3),
                              pack2(xi1 * xj4, xi1 * xj5), pack2(xi1 * xj6, xi1 * xj7));
        unsigned short* pd = Pl + nbuf * 5120 + rl * 40 + h * 16;
        *(uint4*)pd       = o0;   // kl = h*16 + 0..7  (ii = 2h)
        *(uint4*)(pd + 8) = o1;   // kl = h*16 + 8..15 (ii = 2h+1)
    };

    // prime: tile 0 into buf 0; prefetch tile 1 into regs
    build_tile(0, 0, 0);
    {
        uint4 wa = *(const uint4*)(Wp + woff);
        uint4 wb = *(const uint4*)(Wp + woff + 8);
        stage_w(0, wa, wb);
    }
    uint4 wra = *(const uint4*)(Wp + 4096 + woff);
    uint4 wrb = *(const uint4*)(Wp + 4096 + woff + 8);
    __syncthreads();

    int icn = 0, jcn = 1;   // coords of tile 1
    for (int tt = 0; tt < T; ++tt) {
        const int cb = tt & 1;
        const int nb = cb ^ 1;
        if (tt + 1 < T) {
            stage_w(nb, wra, wrb);
            build_tile(nb, icn, jcn);
            if (++jcn == NJC) { jcn = 0; ++icn; }
        }
        if (tt + 2 < T) {
            const unsigned short* w2 = Wp + (size_t)(tt + 2) * 4096 + woff;
            wra = *(const uint4*)w2;
            wrb = *(const uint4*)(w2 + 8);
        }
        uint4 av[4], bv[4];
        #pragma unroll
        for (int mt = 0; mt < 4; ++mt) av[mt] = *(const uint4*)(Pl + cb * 5120 + mt * 640 + abase);
        #pragma unroll
        for (int nt = 0; nt < 4; ++nt) bv[nt] = *(const uint4*)(Wl + cb * 5120 + nt * 640 + bbase);
        #pragma unroll
        for (int mt = 0; mt < 4; ++mt) {
            #pragma unroll
            for (int nt = 0; nt < 4; ++nt) {
                acc[mt][nt] = __builtin_amdgcn_mfma_f32_16x16x32_bf16(
                    __builtin_bit_cast(short8, av[mt]),
                    __builtin_bit_cast(short8, bv[nt]),
                    acc[mt][nt], 0, 0, 0);
            }
        }
        __syncthreads();
    }
}

__global__ __launch_bounds__(256, 2)
void fused_two_layer(const float* __restrict__ x,
                     const unsigned short* __restrict__ W0p,
                     const float* __restrict__ b0,
                     const unsigned short* __restrict__ W1p,
                     const float* __restrict__ b1,
                     float* __restrict__ out)
{
    __shared__ unsigned short Xl[128 * 40];   // [r][i] bf16, 80B rows
    __shared__ unsigned short Pl[2 * 5120];   // P double buffer [2][128][40] (32 used)
    __shared__ unsigned short Wl[2 * 5120];   // W double buffer [2][128][40] (32 used)
    __shared__ unsigned short NH[128 * 64];   // next_hidden [r][j] bf16

    const int tid  = threadIdx.x;
    const int lane = tid & 63;
    const int rl   = tid >> 1;
    const int mw   = (tid >> 6) & 1;
    const int nw   = tid >> 7;
    const int ml   = lane & 15;
    const int quad = lane >> 4;

    // ---- stage X: x[4b][i][d] fp32 -> Xl[(bl*32+d)*40 + i] bf16 (RNE) ----
    const float* xblk = x + (size_t)blockIdx.x * (4 * 40 * 32);
    #pragma unroll
    for (int bl = 0; bl < 4; ++bl) {
        #pragma unroll
        for (int k = 0; k < 5; ++k) {
            int e = 256 * k + tid;         // 0..1279
            int i = e >> 5, d = e & 31;
            Xl[(bl * 32 + d) * 40 + i] = f2bf(xblk[bl * 1280 + e]);
        }
    }
    __syncthreads();

    f32x4 acc[4][4];
    const f32x4 zero4 = {0.f, 0.f, 0.f, 0.f};
    #pragma unroll
    for (int mt = 0; mt < 4; ++mt)
        #pragma unroll
        for (int nt = 0; nt < 4; ++nt) acc[mt][nt] = zero4;

    // ================= phase 0: K=1600 (50 tiles), j from X =================
    gemm_phase(50, 5, W0p, Xl + rl * 40, Xl + rl * 40, Pl, Wl, acc, tid);

    {   // epilogue 0: bias+relu; s<64 -> NH (LDS); s>=64 -> d-reduce -> out[:,0:64]
        float bias[4];
        #pragma unroll
        for (int nt = 0; nt < 4; ++nt) bias[nt] = b0[nw * 64 + nt * 16 + ml];
        if (nw == 0) {
            #pragma unroll
            for (int mt = 0; mt < 4; ++mt) {
                int r = mw * 64 + mt * 16 + (quad << 2);
                #pragma unroll
                for (int nt = 0; nt < 4; ++nt) {
                    int s = nt * 16 + ml;
                    #pragma unroll
                    for (int rg = 0; rg < 4; ++rg) {
                        float v = fmaxf(acc[mt][nt][rg] + bias[nt], 0.0f);
                        NH[(r + rg) * 64 + s] = f2bf(v);
                    }
                }
            }
        } else {
            int bb = blockIdx.x * 4 + mw * 2;
            #pragma unroll
            for (int nt = 0; nt < 4; ++nt) {
                float sA = 0.f, sB = 0.f;
                #pragma unroll
                for (int rg = 0; rg < 4; ++rg) {
                    sA += fmaxf(acc[0][nt][rg] + bias[nt], 0.f) + fmaxf(acc[1][nt][rg] + bias[nt], 0.f);
                    sB += fmaxf(acc[2][nt][rg] + bias[nt], 0.f) + fmaxf(acc[3][nt][rg] + bias[nt], 0.f);
                }
                sA = qsum(sA); sB = qsum(sB);
                if (lane < 16) {
                    out[(size_t)bb * 192 + nt * 16 + lane]       = sA;
                    out[(size_t)(bb + 1) * 192 + nt * 16 + lane] = sB;
                }
            }
        }
    }
    __syncthreads();   // NH visible before phase-1 builds read it

    #pragma unroll
    for (int mt = 0; mt < 4; ++mt)
        #pragma unroll
        for (int nt = 0; nt < 4; ++nt) acc[mt][nt] = zero4;

    // ================= phase 1: K=2560 (80 tiles), j from NH ================
    gemm_phase(80, 8, W1p, NH + rl * 64, Xl + rl * 40, Pl, Wl, acc, tid);

    {   // epilogue 1: bias+relu; d-reduce -> out[:, 64:192]
        float bias[4];
        #pragma unroll
        for (int nt = 0; nt < 4; ++nt) bias[nt] = b1[nw * 64 + nt * 16 + ml];
        int bb = blockIdx.x * 4 + mw * 2;
        #pragma unroll
        for (int nt = 0; nt < 4; ++nt) {
            float sA = 0.f, sB = 0.f;
            #pragma unroll
            for (int rg = 0; rg < 4; ++rg) {
                sA += fmaxf(acc[0][nt][rg] + bias[nt], 0.f) + fmaxf(acc[1][nt][rg] + bias[nt], 0.f);
                sB += fmaxf(acc[2][nt][rg] + bias[nt], 0.f) + fmaxf(acc[3][nt][rg] + bias[nt], 0.f);
            }
            sA = qsum(sA); sB = qsum(sB);
            if (lane < 16) {
                out[(size_t)bb * 192 + 64 + nw * 64 + nt * 16 + lane]       = sA;
                out[(size_t)(bb + 1) * 192 + 64 + nw * 64 + nt * 16 + lane] = sB;
            }
        }
    }
}

extern "C" void kernel_launch(void* const* d_in, const int* in_sizes, int n_in,
                              void* d_out, int out_size, void* d_ws, size_t ws_size,
                              hipStream_t stream) {
    const float* x  = (const float*)d_in[0];   // [2048][40][32]
    const float* W0 = (const float*)d_in[1];   // [40][40][128]
    const float* b0 = (const float*)d_in[2];   // [128]
    const float* W1 = (const float*)d_in[3];   // [40][64][128]
    const float* b1 = (const float*)d_in[4];   // [128]
    float* out = (float*)d_out;                // [2048][192]

    unsigned short* W0p = (unsigned short*)d_ws;                          // 50*128*32 bf16 = 409600 B
    unsigned short* W1p = (unsigned short*)((char*)d_ws + 50 * 4096 * 2); // 80*128*32 bf16 = 655360 B

    permute_w<5, 40><<<(204800 + 255) / 256, 256, 0, stream>>>(W0, W0p, 204800);
    permute_w<8, 64><<<(327680 + 255) / 256, 256, 0, stream>>>(W1, W1p, 327680);
    fused_two_layer<<<512, 256, 0, stream>>>(x, W0p, b0, W1p, b1, out);
}

// Round 3
// 138.006 us; speedup vs baseline: 1.1641x; 1.1641x over previous
//
#include <hip/hip_runtime.h>
#include <stdint.h>

// ---------------------------------------------------------------------------
// B=2048, F0=40, D=32, LAYER0=LAYER1=128.  Rows r=b*32+d (65536).
//   phase0: h0[r,s] = relu(sum_{i<40,j<40} X[r,i]X[r,j] W0[i,j,s] + b0[s])
//   phase1: d1[r,s] = relu(sum_{i<40,j<64} X[r,i]NH[r,j] W1[i,j,s] + b1[s])
//   out[b,0:64] = sum_d h0[:,64:128]; out[b,64:192] = sum_d d1
//
// Round-3 structure: A-fragments BUILT IN REGISTERS (no P tile in LDS, no
// k-loop barriers).  For mfma 16x16x32 a lane's A-frag is
//   A[m=ml][k=kq..kq+7],  kq=(lane>>4)*8;  k-mapping kl=ii*8+jj  =>
//   ii = lane>>4 (lane-constant), frag = xi[ic] * xj[jc*8..+7]  (scalar*vec8).
// B-fragments read directly from global Wp (1MB, L2-resident; all 512 blocks
// stream it in the same order).  Wp tile order is jc-major (t = jc*10+ic) so
// the 16B jv LDS read amortizes over 10 consecutive k-steps.
// Round-2 failure mode this fixes: 12 b128 DS ops/thread/step (~1152 LDS
// cyc/CU/step vs 516 MFMA cyc) + 2e7 bank-conflict cycles + 130 barriers.
// ---------------------------------------------------------------------------

typedef __attribute__((ext_vector_type(8))) short short8;
typedef __attribute__((ext_vector_type(4))) float f32x4;

__device__ __forceinline__ float bf2f(unsigned short v) {
    return __uint_as_float(((unsigned int)v) << 16);
}
__device__ __forceinline__ unsigned short f2bf(float f) {   // RNE
    unsigned int u = __float_as_uint(f);
    u += 0x7FFFu + ((u >> 16) & 1u);
    return (unsigned short)(u >> 16);
}
// two f32 -> packed bf16 pair, round-half-away (+0x8000).  Differs from RNE
// only on exact ties (prob ~2^-8 for bf16*bf16 products) -> negligible bias;
// 3 VALU vs RNE's 7.  (Truncation's coherent bias cost us round 1.)
__device__ __forceinline__ unsigned int packhu(float lo, float hi) {
    unsigned int a = __float_as_uint(lo) + 0x8000u;
    unsigned int b = __float_as_uint(hi) + 0x8000u;
    return __builtin_amdgcn_perm(b, a, 0x07060302u);  // [hi16(b) : hi16(a)]
}
__device__ __forceinline__ float qsum(float v) {  // reduce across row-quads
    v += __shfl_xor(v, 16, 64);
    v += __shfl_xor(v, 32, 64);
    return v;
}

// Single permute kernel, coalesced reads: block e <-> (i,j), threads = s.
// Wp[t][s][kl] = bf16(W[i,j,s]), t = (j>>3)*10 + (i>>2), kl = (i&3)*8 + (j&7).
__global__ void permute_w_both(const float* __restrict__ W0, const float* __restrict__ W1,
                               unsigned short* __restrict__ Wp0, unsigned short* __restrict__ Wp1)
{
    int e = blockIdx.x;
    int s = threadIdx.x;
    if (e < 1600) {                       // W0: 40x40
        int i = e / 40, j = e - i * 40;
        int t = (j >> 3) * 10 + (i >> 2);
        int kl = (i & 3) * 8 + (j & 7);
        Wp0[t * 4096 + s * 32 + kl] = f2bf(W0[(size_t)e * 128 + s]);
    } else {                              // W1: 40x64
        int e1 = e - 1600;
        int i = e1 >> 6, j = e1 & 63;
        int t = (j >> 3) * 10 + (i >> 2);
        int kl = (i & 3) * 8 + (j & 7);
        Wp1[t * 4096 + s * 32 + kl] = f2bf(W1[(size_t)e1 * 128 + s]);
    }
}

// One GEMM phase, barrier-free.  NJC j-chunks x 10 i-chunks of k-tiles.
template<int NJC>
__device__ __forceinline__ void gemm_phase_reg(
    const unsigned short* __restrict__ Wp,   // [NJC*10][128][32] bf16, global
    const unsigned short* __restrict__ Jl,   // LDS j-source (Xl or NH)
    int jstride,                             // row stride of Jl in elems
    const float xi[4][10],                   // preloaded X[r_mt, ic*4+ii_lane]
    f32x4 acc[4][4], int tid)
{
    const int lane = tid & 63;
    const int mw = (tid >> 6) & 1;
    const int nw = tid >> 7;
    const int ml = lane & 15;
    const int kc = lane >> 4;                       // k-chunk == ii
    const unsigned short* wt = Wp + ((nw * 64 + ml) * 32 + kc * 8);
    const unsigned short* jrow[4];
    #pragma unroll
    for (int mt = 0; mt < 4; ++mt)
        jrow[mt] = Jl + (mw * 64 + mt * 16 + ml) * jstride;

    uint4 bv[4];                                    // current B frags (tile 0)
    #pragma unroll
    for (int nt = 0; nt < 4; ++nt) bv[nt] = *(const uint4*)(wt + nt * 512);

    for (int jc = 0; jc < NJC; ++jc) {
        float xj[4][8];
        #pragma unroll
        for (int mt = 0; mt < 4; ++mt) {
            uint4 jv = *(const uint4*)(jrow[mt] + jc * 8);
            xj[mt][0] = __uint_as_float(jv.x << 16);
            xj[mt][1] = __uint_as_float(jv.x & 0xFFFF0000u);
            xj[mt][2] = __uint_as_float(jv.y << 16);
            xj[mt][3] = __uint_as_float(jv.y & 0xFFFF0000u);
            xj[mt][4] = __uint_as_float(jv.z << 16);
            xj[mt][5] = __uint_as_float(jv.z & 0xFFFF0000u);
            xj[mt][6] = __uint_as_float(jv.w << 16);
            xj[mt][7] = __uint_as_float(jv.w & 0xFFFF0000u);
        }
        #pragma unroll
        for (int ic = 0; ic < 10; ++ic) {
            // prefetch next tile's B frags (last-of-last reloads current: dead)
            const unsigned short* wn;
            if (ic < 9) wn = wt + 4096;
            else        wn = (jc + 1 < NJC) ? wt + 4096 : wt;
            uint4 bn[4];
            #pragma unroll
            for (int nt = 0; nt < 4; ++nt) bn[nt] = *(const uint4*)(wn + nt * 512);
            // build A frags in registers: scalar * vec8, pack to bf16
            uint4 av[4];
            #pragma unroll
            for (int mt = 0; mt < 4; ++mt) {
                float xs = xi[mt][ic];
                av[mt].x = packhu(xs * xj[mt][0], xs * xj[mt][1]);
                av[mt].y = packhu(xs * xj[mt][2], xs * xj[mt][3]);
                av[mt].z = packhu(xs * xj[mt][4], xs * xj[mt][5]);
                av[mt].w = packhu(xs * xj[mt][6], xs * xj[mt][7]);
            }
            #pragma unroll
            for (int mt = 0; mt < 4; ++mt)
                #pragma unroll
                for (int nt = 0; nt < 4; ++nt)
                    acc[mt][nt] = __builtin_amdgcn_mfma_f32_16x16x32_bf16(
                        __builtin_bit_cast(short8, av[mt]),
                        __builtin_bit_cast(short8, bv[nt]),
                        acc[mt][nt], 0, 0, 0);
            #pragma unroll
            for (int nt = 0; nt < 4; ++nt) bv[nt] = bn[nt];
            wt = wn;
        }
    }
}

__global__ __launch_bounds__(256, 2)
void fused_two_layer(const float* __restrict__ x,
                     const unsigned short* __restrict__ W0p,
                     const float* __restrict__ b0,
                     const unsigned short* __restrict__ W1p,
                     const float* __restrict__ b1,
                     float* __restrict__ out)
{
    __shared__ __align__(16) unsigned short Xl[128 * 40];  // [r][i], 80B rows
    __shared__ __align__(16) unsigned short NH[128 * 72];  // stride 72: 144B
        // = 36 words -> jv b128 reads hit all 32 banks (stride 64 would be
        // 8-way same-bank).

    const int tid  = threadIdx.x;
    const int lane = tid & 63;
    const int mw   = (tid >> 6) & 1;
    const int nw   = tid >> 7;
    const int ml   = lane & 15;
    const int kc   = lane >> 4;

    // ---- stage X: x[4b][i][d] fp32 -> Xl[(bl*32+d)*40 + i] bf16 (RNE) ----
    const float* xblk = x + (size_t)blockIdx.x * (4 * 40 * 32);
    #pragma unroll
    for (int bl = 0; bl < 4; ++bl) {
        #pragma unroll
        for (int k = 0; k < 5; ++k) {
            int e = 256 * k + tid;
            int i = e >> 5, d = e & 31;
            Xl[(bl * 32 + d) * 40 + i] = f2bf(xblk[bl * 1280 + e]);
        }
    }
    __syncthreads();

    // ---- preload this lane's i-scalars (same for both phases) ----
    float xi[4][10];
    #pragma unroll
    for (int mt = 0; mt < 4; ++mt) {
        const unsigned short* xr = Xl + (mw * 64 + mt * 16 + ml) * 40;
        #pragma unroll
        for (int ic = 0; ic < 10; ++ic) xi[mt][ic] = bf2f(xr[ic * 4 + kc]);
    }

    f32x4 acc[4][4];
    const f32x4 zero4 = {0.f, 0.f, 0.f, 0.f};
    #pragma unroll
    for (int mt = 0; mt < 4; ++mt)
        #pragma unroll
        for (int nt = 0; nt < 4; ++nt) acc[mt][nt] = zero4;

    // ================= phase 0: 50 tiles, j from X =================
    gemm_phase_reg<5>(W0p, Xl, 40, xi, acc, tid);

    {   // epilogue 0: bias+relu; s<64 -> NH; s>=64 -> d-reduce -> out[:,0:64]
        float bias[4];
        #pragma unroll
        for (int nt = 0; nt < 4; ++nt) bias[nt] = b0[nw * 64 + nt * 16 + ml];
        if (nw == 0) {
            #pragma unroll
            for (int mt = 0; mt < 4; ++mt) {
                int r = mw * 64 + mt * 16 + (kc << 2);
                #pragma unroll
                for (int nt = 0; nt < 4; ++nt) {
                    int s = nt * 16 + ml;
                    #pragma unroll
                    for (int rg = 0; rg < 4; ++rg) {
                        float v = fmaxf(acc[mt][nt][rg] + bias[nt], 0.0f);
                        NH[(r + rg) * 72 + s] = f2bf(v);
                    }
                }
            }
        } else {
            int bb = blockIdx.x * 4 + mw * 2;
            #pragma unroll
            for (int nt = 0; nt < 4; ++nt) {
                float sA = 0.f, sB = 0.f;
                #pragma unroll
                for (int rg = 0; rg < 4; ++rg) {
                    sA += fmaxf(acc[0][nt][rg] + bias[nt], 0.f) + fmaxf(acc[1][nt][rg] + bias[nt], 0.f);
                    sB += fmaxf(acc[2][nt][rg] + bias[nt], 0.f) + fmaxf(acc[3][nt][rg] + bias[nt], 0.f);
                }
                sA = qsum(sA); sB = qsum(sB);
                if (lane < 16) {
                    out[(size_t)bb * 192 + nt * 16 + lane]       = sA;
                    out[(size_t)(bb + 1) * 192 + nt * 16 + lane] = sB;
                }
            }
        }
    }
    __syncthreads();   // NH visible to all waves

    #pragma unroll
    for (int mt = 0; mt < 4; ++mt)
        #pragma unroll
        for (int nt = 0; nt < 4; ++nt) acc[mt][nt] = zero4;

    // ================= phase 1: 80 tiles, j from NH ================
    gemm_phase_reg<8>(W1p, NH, 72, xi, acc, tid);

    {   // epilogue 1: bias+relu; d-reduce -> out[:, 64:192]
        float bias[4];
        #pragma unroll
        for (int nt = 0; nt < 4; ++nt) bias[nt] = b1[nw * 64 + nt * 16 + ml];
        int bb = blockIdx.x * 4 + mw * 2;
        #pragma unroll
        for (int nt = 0; nt < 4; ++nt) {
            float sA = 0.f, sB = 0.f;
            #pragma unroll
            for (int rg = 0; rg < 4; ++rg) {
                sA += fmaxf(acc[0][nt][rg] + bias[nt], 0.f) + fmaxf(acc[1][nt][rg] + bias[nt], 0.f);
                sB += fmaxf(acc[2][nt][rg] + bias[nt], 0.f) + fmaxf(acc[3][nt][rg] + bias[nt], 0.f);
            }
            sA = qsum(sA); sB = qsum(sB);
            if (lane < 16) {
                out[(size_t)bb * 192 + 64 + nw * 64 + nt * 16 + lane]       = sA;
                out[(size_t)(bb + 1) * 192 + 64 + nw * 64 + nt * 16 + lane] = sB;
            }
        }
    }
}

extern "C" void kernel_launch(void* const* d_in, const int* in_sizes, int n_in,
                              void* d_out, int out_size, void* d_ws, size_t ws_size,
                              hipStream_t stream) {
    const float* x  = (const float*)d_in[0];   // [2048][40][32]
    const float* W0 = (const float*)d_in[1];   // [40][40][128]
    const float* b0 = (const float*)d_in[2];   // [128]
    const float* W1 = (const float*)d_in[3];   // [40][64][128]
    const float* b1 = (const float*)d_in[4];   // [128]
    float* out = (float*)d_out;                // [2048][192]

    unsigned short* W0p = (unsigned short*)d_ws;                          // 50*4096*2 = 409600 B
    unsigned short* W1p = (unsigned short*)((char*)d_ws + 50 * 4096 * 2); // 80*4096*2 = 655360 B

    permute_w_both<<<1600 + 2560, 128, 0, stream>>>(W0, W1, W0p, W1p);
    fused_two_layer<<<512, 256, 0, stream>>>(x, W0p, b0, W1p, b1, out);
}

// Round 5
// 128.956 us; speedup vs baseline: 1.2458x; 1.0702x over previous
//
#include <hip/hip_runtime.h>
#include <stdint.h>

// ---------------------------------------------------------------------------
// B=2048, F0=40, D=32, LAYER0=LAYER1=128.  Rows r=b*32+d (65536).
//   phase0: h0[r,s] = relu(sum_{i<40,j<40} X[r,i]X[r,j] W0[i,j,s] + b0[s])
//   phase1: d1[r,s] = relu(sum_{i<40,j<64} X[r,i]NH[r,j] W1[i,j,s] + b1[s])
//   out[b,0:64] = sum_d h0[:,64:128]; out[b,64:192] = sum_d d1
//
// Round-5 = round-4 + permute store fix (round 4 wrote only 16 of each
// thread's 32 output bytes -> odd-ii weight slices stayed 0xAA poison).
//
// FP16 datapath: A-fragments built in registers with ONE v_pk_mul_f16 per
// element-pair (xj stays packed, xi preloaded as broadcast half2).  This is
// the fix for round-3's VALUBusy 58% > MfmaUtil 35% (80-op, 5-stage A-build
// chain per 16 MFMAs).  fp16: 10-bit mantissa (8x tighter than bf16); range
// safe (|x|<=5.2, |P1|<~650 << 65504).  mfma_f32_16x16x32_f16, f32 acc.
// B-frags stream from L2-resident Wp (1 MB), prefetched one tile ahead; jv
// LDS reads pipelined one jc-chunk ahead.  No k-loop barriers.
// ---------------------------------------------------------------------------

typedef __attribute__((ext_vector_type(8))) _Float16 half8;
typedef __attribute__((ext_vector_type(2))) _Float16 half2v;
typedef __attribute__((ext_vector_type(4))) float f32x4;

__device__ __forceinline__ unsigned short f2h(float f) {   // v_cvt_f16_f32, RNE
    return __builtin_bit_cast(unsigned short, (_Float16)f);
}
__device__ __forceinline__ float qsum(float v) {  // reduce across row-quads
    v += __shfl_xor(v, 16, 64);
    v += __shfl_xor(v, 32, 64);
    return v;
}

// Permute W -> Wp[t][s][kl] fp16, t = jc*10+ic, kl = ii*8+jj, i=ic*4+ii,
// j=jc*8+jj.  One block per tile t; thread = (s, h) writes 32B contiguous.
__global__ void permute_w_both(const float* __restrict__ W0, const float* __restrict__ W1,
                               unsigned short* __restrict__ Wp0, unsigned short* __restrict__ Wp1)
{
    int t = blockIdx.x;
    int s = threadIdx.x >> 1, h = threadIdx.x & 1;
    const float* W; unsigned short* Wp; int JW, tt;
    if (t < 50) { W = W0; Wp = Wp0; JW = 40; tt = t; }
    else        { W = W1; Wp = Wp1; JW = 64; tt = t - 50; }
    int jc = tt / 10, ic = tt - jc * 10;
    unsigned short outv[16];
    #pragma unroll
    for (int q = 0; q < 16; ++q) {
        int kl = h * 16 + q;
        int i = ic * 4 + (kl >> 3), j = jc * 8 + (kl & 7);
        outv[q] = f2h(W[((size_t)(i * JW + j)) * 128 + s]);
    }
    unsigned short* dst = Wp + (size_t)tt * 4096 + s * 32 + h * 16;
    *(uint4*)dst       = *(const uint4*)outv;        // bytes 0..15  (kl h*16+0..7)
    *(uint4*)(dst + 8) = *(const uint4*)(outv + 8);  // bytes 16..31 (kl h*16+8..15)
        // ^ round-4 bug: this second store was missing; outv is 32 B.
}

// One GEMM phase, barrier-free.  NJC j-chunks x 10 i-chunks of k-tiles.
template<int NJC>
__device__ __forceinline__ void gemm_phase_reg(
    const unsigned short* __restrict__ Wp,   // [NJC*10][128][32] fp16, global
    const unsigned short* __restrict__ Jl,   // LDS j-source (Xl or NH)
    int jstride,                             // row stride of Jl in elems
    const unsigned int xi2[4][10],           // broadcast half2 of X[r_mt, ic*4+kc]
    f32x4 acc[4][4], int tid)
{
    const int lane = tid & 63;
    const int mw = (tid >> 6) & 1;
    const int nw = tid >> 7;
    const int ml = lane & 15;
    const int kc = lane >> 4;                       // k-chunk == ii
    const unsigned short* wt = Wp + ((nw * 64 + ml) * 32 + kc * 8);
    const unsigned short* jrow[4];
    #pragma unroll
    for (int mt = 0; mt < 4; ++mt)
        jrow[mt] = Jl + (mw * 64 + mt * 16 + ml) * jstride;

    uint4 bv[4];                                    // current B frags (tile 0)
    #pragma unroll
    for (int nt = 0; nt < 4; ++nt) bv[nt] = *(const uint4*)(wt + nt * 512);

    uint4 jv[4], jvn[4];                            // jc-chunk j-values (packed fp16)
    #pragma unroll
    for (int mt = 0; mt < 4; ++mt) jv[mt] = *(const uint4*)(jrow[mt]);

    for (int jc = 0; jc < NJC; ++jc) {
        if (jc + 1 < NJC) {                         // prefetch next jc's j-values
            #pragma unroll
            for (int mt = 0; mt < 4; ++mt) jvn[mt] = *(const uint4*)(jrow[mt] + (jc + 1) * 8);
        } else {
            #pragma unroll
            for (int mt = 0; mt < 4; ++mt) jvn[mt] = jv[mt];   // keep defined (dead)
        }
        #pragma unroll
        for (int ic = 0; ic < 10; ++ic) {
            // prefetch next tile's B frags (last-of-last reloads current: dead)
            const unsigned short* wn;
            if (ic < 9) wn = wt + 4096;
            else        wn = (jc + 1 < NJC) ? wt + 4096 : wt;
            uint4 bn[4];
            #pragma unroll
            for (int nt = 0; nt < 4; ++nt) bn[nt] = *(const uint4*)(wn + nt * 512);
            // A frags: one v_pk_mul_f16 per pair (xi broadcast * packed xj)
            uint4 av[4];
            #pragma unroll
            for (int mt = 0; mt < 4; ++mt) {
                half2v x2 = __builtin_bit_cast(half2v, xi2[mt][ic]);
                av[mt].x = __builtin_bit_cast(unsigned int,
                    (half2v)(x2 * __builtin_bit_cast(half2v, jv[mt].x)));
                av[mt].y = __builtin_bit_cast(unsigned int,
                    (half2v)(x2 * __builtin_bit_cast(half2v, jv[mt].y)));
                av[mt].z = __builtin_bit_cast(unsigned int,
                    (half2v)(x2 * __builtin_bit_cast(half2v, jv[mt].z)));
                av[mt].w = __builtin_bit_cast(unsigned int,
                    (half2v)(x2 * __builtin_bit_cast(half2v, jv[mt].w)));
            }
            #pragma unroll
            for (int mt = 0; mt < 4; ++mt)
                #pragma unroll
                for (int nt = 0; nt < 4; ++nt)
                    acc[mt][nt] = __builtin_amdgcn_mfma_f32_16x16x32_f16(
                        __builtin_bit_cast(half8, av[mt]),
                        __builtin_bit_cast(half8, bv[nt]),
                        acc[mt][nt], 0, 0, 0);
            #pragma unroll
            for (int nt = 0; nt < 4; ++nt) bv[nt] = bn[nt];
            wt = wn;
        }
        #pragma unroll
        for (int mt = 0; mt < 4; ++mt) jv[mt] = jvn[mt];
    }
}

__global__ __launch_bounds__(256, 2)
void fused_two_layer(const float* __restrict__ x,
                     const unsigned short* __restrict__ W0p,
                     const float* __restrict__ b0,
                     const unsigned short* __restrict__ W1p,
                     const float* __restrict__ b1,
                     float* __restrict__ out)
{
    __shared__ __align__(16) unsigned short Xl[128 * 40];  // [r][i] fp16, 80B rows
    __shared__ __align__(16) unsigned short NH[128 * 72];  // stride 72 (jv b128
        // reads at 144B row stride walk all banks; 128B stride would be 8-way)

    const int tid  = threadIdx.x;
    const int lane = tid & 63;
    const int mw   = (tid >> 6) & 1;
    const int nw   = tid >> 7;
    const int ml   = lane & 15;
    const int kc   = lane >> 4;

    // ---- stage X: x[4b][i][d] fp32 -> Xl[(bl*32+d)*40 + i] fp16 (RNE) ----
    const float* xblk = x + (size_t)blockIdx.x * (4 * 40 * 32);
    #pragma unroll
    for (int bl = 0; bl < 4; ++bl) {
        #pragma unroll
        for (int k = 0; k < 5; ++k) {
            int e = 256 * k + tid;
            int i = e >> 5, d = e & 31;
            Xl[(bl * 32 + d) * 40 + i] = f2h(xblk[bl * 1280 + e]);
        }
    }
    __syncthreads();

    // ---- preload this lane's i-scalars as broadcast half2 (both phases) ----
    unsigned int xi2[4][10];
    #pragma unroll
    for (int mt = 0; mt < 4; ++mt) {
        const unsigned short* xr = Xl + (mw * 64 + mt * 16 + ml) * 40;
        #pragma unroll
        for (int ic = 0; ic < 10; ++ic) {
            unsigned int u = xr[ic * 4 + kc];
            xi2[mt][ic] = u | (u << 16);
        }
    }

    f32x4 acc[4][4];
    const f32x4 zero4 = {0.f, 0.f, 0.f, 0.f};
    #pragma unroll
    for (int mt = 0; mt < 4; ++mt)
        #pragma unroll
        for (int nt = 0; nt < 4; ++nt) acc[mt][nt] = zero4;

    // ================= phase 0: 50 tiles, j from X =================
    gemm_phase_reg<5>(W0p, Xl, 40, xi2, acc, tid);

    {   // epilogue 0: bias+relu; s<64 -> NH; s>=64 -> d-reduce -> out[:,0:64]
        float bias[4];
        #pragma unroll
        for (int nt = 0; nt < 4; ++nt) bias[nt] = b0[nw * 64 + nt * 16 + ml];
        if (nw == 0) {
            #pragma unroll
            for (int mt = 0; mt < 4; ++mt) {
                int r = mw * 64 + mt * 16 + (kc << 2);
                #pragma unroll
                for (int nt = 0; nt < 4; ++nt) {
                    int s = nt * 16 + ml;
                    #pragma unroll
                    for (int rg = 0; rg < 4; ++rg) {
                        float v = fmaxf(acc[mt][nt][rg] + bias[nt], 0.0f);
                        NH[(r + rg) * 72 + s] = f2h(v);
                    }
                }
            }
        } else {
            int bb = blockIdx.x * 4 + mw * 2;
            #pragma unroll
            for (int nt = 0; nt < 4; ++nt) {
                float sA = 0.f, sB = 0.f;
                #pragma unroll
                for (int rg = 0; rg < 4; ++rg) {
                    sA += fmaxf(acc[0][nt][rg] + bias[nt], 0.f) + fmaxf(acc[1][nt][rg] + bias[nt], 0.f);
                    sB += fmaxf(acc[2][nt][rg] + bias[nt], 0.f) + fmaxf(acc[3][nt][rg] + bias[nt], 0.f);
                }
                sA = qsum(sA); sB = qsum(sB);
                if (lane < 16) {
                    out[(size_t)bb * 192 + nt * 16 + lane]       = sA;
                    out[(size_t)(bb + 1) * 192 + nt * 16 + lane] = sB;
                }
            }
        }
    }
    __syncthreads();   // NH visible to all waves

    #pragma unroll
    for (int mt = 0; mt < 4; ++mt)
        #pragma unroll
        for (int nt = 0; nt < 4; ++nt) acc[mt][nt] = zero4;

    // ================= phase 1: 80 tiles, j from NH ================
    gemm_phase_reg<8>(W1p, NH, 72, xi2, acc, tid);

    {   // epilogue 1: bias+relu; d-reduce -> out[:, 64:192]
        float bias[4];
        #pragma unroll
        for (int nt = 0; nt < 4; ++nt) bias[nt] = b1[nw * 64 + nt * 16 + ml];
        int bb = blockIdx.x * 4 + mw * 2;
        #pragma unroll
        for (int nt = 0; nt < 4; ++nt) {
            float sA = 0.f, sB = 0.f;
            #pragma unroll
            for (int rg = 0; rg < 4; ++rg) {
                sA += fmaxf(acc[0][nt][rg] + bias[nt], 0.f) + fmaxf(acc[1][nt][rg] + bias[nt], 0.f);
                sB += fmaxf(acc[2][nt][rg] + bias[nt], 0.f) + fmaxf(acc[3][nt][rg] + bias[nt], 0.f);
            }
            sA = qsum(sA); sB = qsum(sB);
            if (lane < 16) {
                out[(size_t)bb * 192 + 64 + nw * 64 + nt * 16 + lane]       = sA;
                out[(size_t)(bb + 1) * 192 + 64 + nw * 64 + nt * 16 + lane] = sB;
            }
        }
    }
}

extern "C" void kernel_launch(void* const* d_in, const int* in_sizes, int n_in,
                              void* d_out, int out_size, void* d_ws, size_t ws_size,
                              hipStream_t stream) {
    const float* x  = (const float*)d_in[0];   // [2048][40][32]
    const float* W0 = (const float*)d_in[1];   // [40][40][128]
    const float* b0 = (const float*)d_in[2];   // [128]
    const float* W1 = (const float*)d_in[3];   // [40][64][128]
    const float* b1 = (const float*)d_in[4];   // [128]
    float* out = (float*)d_out;                // [2048][192]

    unsigned short* W0p = (unsigned short*)d_ws;                          // 50*4096*2 = 409600 B
    unsigned short* W1p = (unsigned short*)((char*)d_ws + 50 * 4096 * 2); // 80*4096*2 = 655360 B

    permute_w_both<<<130, 256, 0, stream>>>(W0, W1, W0p, W1p);
    fused_two_layer<<<512, 256, 0, stream>>>(x, W0p, b0, W1p, b1, out);
}